// Round 7
// baseline (359.099 us; speedup 1.0000x reference)
//
#include <hip/hip_runtime.h>
#include <hip/hip_bf16.h>

constexpr int B_  = 8;
constexpr int N1_ = 8192;
constexpr int N2_ = 2048;
constexpr int K_  = 8;

typedef short bf16x8 __attribute__((ext_vector_type(8)));
typedef float f32x4  __attribute__((ext_vector_type(4)));

__device__ __forceinline__ short f2b(float x) {
    __hip_bfloat16 h = __float2bfloat16(x);  // RNE
    return *reinterpret_cast<short*>(&h);
}

// ---------------------------------------------------------------------------
// Prep 1: feat2 f32 -> bf16 (2M elems), 4 per thread.
// ---------------------------------------------------------------------------
__global__ __launch_bounds__(256) void prep_feat2(const float* __restrict__ feat2,
                                                  short* __restrict__ feat2b) {
    const int i = blockIdx.x * 256 + threadIdx.x;  // 524288 threads
    const float4 v = ((const float4*)feat2)[i];
    uint2 o;
    o.x = (unsigned short)f2b(v.x) | ((unsigned)(unsigned short)f2b(v.y) << 16);
    o.y = (unsigned short)f2b(v.z) | ((unsigned)(unsigned short)f2b(v.w) << 16);
    ((uint2*)feat2b)[i] = o;
}

// ---------------------------------------------------------------------------
// Prep 2: weights -> transposed bf16 [n][k] (k contiguous), W0 k-padded with
// zeros to 160; also pack xyz2 into float4 for scalar-load KNN.
// ---------------------------------------------------------------------------
__global__ __launch_bounds__(256) void prep_weights(
    const float* __restrict__ W0, const float* __restrict__ W1,
    const float* __restrict__ W2, const float* __restrict__ xyz2,
    short* __restrict__ W0T, short* __restrict__ W1T, short* __restrict__ W2T,
    float4* __restrict__ xpack) {
    int i = blockIdx.x * 256 + threadIdx.x;  // 304*256 = 77824 threads
    if (i < 128 * 160) {
        const int n = i / 160, k = i % 160;
        W0T[i] = (k < 131) ? f2b(W0[k * 128 + n]) : (short)0;
        return;
    }
    i -= 128 * 160;
    if (i < 128 * 128) {
        const int n = i >> 7, k = i & 127;
        W1T[i] = f2b(W1[k * 128 + n]);
        return;
    }
    i -= 128 * 128;
    if (i < 128 * 192) {
        const int n = i / 192, k = i % 192;
        W2T[i] = f2b(W2[k * 128 + n]);
        return;
    }
    i -= 128 * 192;
    // 8*2048 xyz2 points
    xpack[i] = make_float4(xyz2[i * 3 + 0], xyz2[i * 3 + 1], xyz2[i * 3 + 2], 0.f);
}

// ---------------------------------------------------------------------------
// KNN v4: same grid/segments as verified v3 (block = 64 queries x 4 segments
// of 512). Per-thread scan keeps a VALUE-ONLY top-8 (u32 bits of d2, monotone
// for >=0 floats) with an unconditional min/max bubble (branch-free), and
// appends accepted j's to a per-thread LDS list. A short recovery pass
// replays the ORIGINAL verified (d,idx) chain over the listed candidates
// only. Equivalence: value multiset == full-chain multiset => identical
// bd[7] evolution => identical accept set => recovery reproduces the original
// stable top-8 bit-exactly. CAP overflow falls back to the full verified scan.
// ---------------------------------------------------------------------------
constexpr int LCAP = 76;   // data slots 0..75; 76,77 = trash (stride 78)

__global__ __launch_bounds__(256) void knn_list(const float* __restrict__ xyz1,
                                                const float4* __restrict__ xpack,
                                                int* __restrict__ idx) {
    __shared__ __align__(16) unsigned short sMem[256 * 78];  // 39936 B
    float* sD = (float*)sMem;             // [64][33] after recovery
    int*   sI = (int*)sMem + 64 * 33;

    const int b = blockIdx.y;
    const int lane = threadIdx.x & 63;   // query within block
    const int s = threadIdx.x >> 6;      // segment 0..3
    const int tid = threadIdx.x;
    const int n = blockIdx.x * 64 + lane;

    const float* q = xyz1 + ((size_t)b * N1_ + n) * 3;
    const float qx = q[0], qy = q[1], qz = q[2];
    const float4* P = xpack + (size_t)b * N2_ + s * 512;

    unsigned bd[K_];
#pragma unroll
    for (int t = 0; t < K_; ++t) bd[t] = __float_as_uint(3.0e38f);
    int cnt = 0;

    for (int j0 = 0; j0 < 512; j0 += 8) {
        float d2[8];
#pragma unroll
        for (int u = 0; u < 8; ++u) {
#pragma clang fp contract(off)
            const float4 p = P[j0 + u];
            const float dx = qx - p.x;
            const float dy = qy - p.y;
            const float dz = qz - p.z;
            const float dx2 = dx * dx;
            const float dy2 = dy * dy;
            const float dz2 = dz * dz;
            d2[u] = (dx2 + dy2) + dz2;
        }
#pragma unroll
        for (int u = 0; u < 8; ++u) {
            const unsigned xu = __float_as_uint(d2[u]);
            const bool acc = xu < bd[K_ - 1];
            const int slot = acc ? (cnt < LCAP ? cnt : LCAP) : LCAP + 1;
            sMem[tid * 78 + slot] = (unsigned short)(j0 + u);
            cnt += acc ? 1 : 0;
            // unconditional value bubble (idempotent when !acc)
            bd[K_ - 1] = bd[K_ - 1] < xu ? bd[K_ - 1] : xu;
#pragma unroll
            for (int t = K_ - 1; t >= 1; --t) {
                const unsigned lo = bd[t - 1] < bd[t] ? bd[t - 1] : bd[t];
                const unsigned hi = bd[t - 1] < bd[t] ? bd[t] : bd[t - 1];
                bd[t - 1] = lo; bd[t] = hi;
            }
        }
    }

    // ---- recovery: replay the verified (d,idx) chain over listed candidates ----
    float rd[K_];
    int   ri[K_];
#pragma unroll
    for (int t = 0; t < K_; ++t) { rd[t] = 3.0e38f; ri[t] = 0; }
    const int m = cnt < LCAP ? cnt : LCAP;
    for (int t = 0;; ++t) {
        const bool act = t < m;
        if (!__any(act)) break;
        if (act) {
#pragma clang fp contract(off)
            const int jl = sMem[tid * 78 + t];
            const float4 p = P[jl];
            const float dx = qx - p.x;
            const float dy = qy - p.y;
            const float dz = qz - p.z;
            const float dx2 = dx * dx;
            const float dy2 = dy * dy;
            const float dz2 = dz * dz;
            const float d2 = (dx2 + dy2) + dz2;
            if (d2 < rd[K_ - 1]) {
                rd[K_ - 1] = d2; ri[K_ - 1] = s * 512 + jl;
#pragma unroll
                for (int t2 = K_ - 1; t2 >= 1; --t2) {
                    if (rd[t2] < rd[t2 - 1]) {
                        float td = rd[t2]; rd[t2] = rd[t2 - 1]; rd[t2 - 1] = td;
                        int   ti = ri[t2]; ri[t2] = ri[t2 - 1]; ri[t2 - 1] = ti;
                    }
                }
            }
        }
    }

    // ---- overflow fallback: full verified scan for the (rare) lane ----
    if (__any(cnt > LCAP)) {
        if (cnt > LCAP) {
#pragma unroll
            for (int t = 0; t < K_; ++t) { rd[t] = 3.0e38f; ri[t] = 0; }
            for (int j = 0; j < 512; ++j) {
#pragma clang fp contract(off)
                const float4 p = P[j];
                const float dx = qx - p.x;
                const float dy = qy - p.y;
                const float dz = qz - p.z;
                const float dx2 = dx * dx;
                const float dy2 = dy * dy;
                const float dz2 = dz * dz;
                const float d2 = (dx2 + dy2) + dz2;
                if (d2 < rd[K_ - 1]) {
                    rd[K_ - 1] = d2; ri[K_ - 1] = s * 512 + j;
#pragma unroll
                    for (int t2 = K_ - 1; t2 >= 1; --t2) {
                        if (rd[t2] < rd[t2 - 1]) {
                            float td = rd[t2]; rd[t2] = rd[t2 - 1]; rd[t2 - 1] = td;
                            int   ti = ri[t2]; ri[t2] = ri[t2 - 1]; ri[t2 - 1] = ti;
                        }
                    }
                }
            }
        }
    }

    __syncthreads();  // lists fully consumed before reusing sMem as merge region
#pragma unroll
    for (int t = 0; t < K_; ++t) {
        sD[lane * 33 + s * 8 + t] = rd[t];
        sI[lane * 33 + s * 8 + t] = ri[t];
    }
    __syncthreads();

    if (tid < 64) {
        const int qq = tid;
        int h[4] = {0, 0, 0, 0};
        const int base = (b * N1_ + n) * K_;
#pragma unroll
        for (int t = 0; t < K_; ++t) {
            float best = 3.1e38f;
            int   bidx = 0, bs = 0;
#pragma unroll
            for (int ss = 0; ss < 4; ++ss) {
                if (h[ss] < 8) {
                    const float d = sD[qq * 33 + ss * 8 + h[ss]];
                    if (d < best) { best = d; bidx = sI[qq * 33 + ss * 8 + h[ss]]; bs = ss; }
                }
            }
            h[bs]++;
            idx[base + t] = bidx;
        }
    }
}

// ---------------------------------------------------------------------------
// Fused MFMA MLP v2: block = 256 thr (4 waves) = 16 points = 128 GEMM rows.
// L0's A-fragments load DIRECTLY from global feat2b (L2-hot); the xyz-diff
// k-block (128..159) is a register-built fragment. A0 LDS staging and its
// barriers are gone. L1/pool/L2 unchanged from the verified round-3 kernel.
// MFMA 16x16x32 bf16; C/D: col=lane&15, row=(lane>>4)*4+reg  [m89-verified]
//      A: A[m=lane&15][k=(lane>>4)*8+j]                      [m120-verified]
// ---------------------------------------------------------------------------
__global__ __launch_bounds__(256) void fused_mfma(
    const float* __restrict__ xyz1, const float* __restrict__ xyz2,
    const float* __restrict__ feat1,
    const float* __restrict__ b0, const float* __restrict__ b1,
    const float* __restrict__ b2,
    const short* __restrict__ feat2b, const short* __restrict__ W0T,
    const short* __restrict__ W1T, const short* __restrict__ W2T,
    const int* __restrict__ idx, float* __restrict__ out) {
    __shared__ __align__(16) short sA1[128 * 136];  // 34816 B
    __shared__ __align__(16) short sCat[16 * 200];  // 6400 B

    const int b = blockIdx.y;
    const int n0 = blockIdx.x * 16;
    const int tid = threadIdx.x;
    const int wave = tid >> 6, lane = tid & 63;
    const int q = lane >> 4, l15 = lane & 15;
    const int mBase = (wave & 1) * 64, nBase = (wave >> 1) * 64;

    // ---- stage feat1 -> sCat cols 128..191 ----
#pragma unroll
    for (int u = 0; u < 4; ++u) {
        const int e = tid * 4 + u;  // 0..1023
        const int p = e >> 6, c = e & 63;
        sCat[p * 200 + 128 + c] = f2b(feat1[((size_t)b * N1_ + n0 + p) * 64 + c]);
    }

    // ---- neighbor indices for this lane's 4 A-rows ----
    int jrow[4];
#pragma unroll
    for (int mt = 0; mt < 4; ++mt) {
        const int row = mBase + mt * 16 + l15;
        const int p = row >> 3, kk = row & 7;
        jrow[mt] = idx[((size_t)b * N1_ + (n0 + p)) * K_ + kk];
    }

    // ---- register-built ks=4 A-fragments (k = 128 + q*8 + j) ----
    bf16x8 a4[4];
#pragma unroll
    for (int mt = 0; mt < 4; ++mt) {
        bf16x8 v = {0, 0, 0, 0, 0, 0, 0, 0};
        if (q == 0) {
            const int row = mBase + mt * 16 + l15;
            const int p = row >> 3;
            const int n = n0 + p;
            const int j = jrow[mt];
            const float dx = xyz2[((size_t)b * N2_ + j) * 3 + 0] - xyz1[((size_t)b * N1_ + n) * 3 + 0];
            const float dy = xyz2[((size_t)b * N2_ + j) * 3 + 1] - xyz1[((size_t)b * N1_ + n) * 3 + 1];
            const float dz = xyz2[((size_t)b * N2_ + j) * 3 + 2] - xyz1[((size_t)b * N1_ + n) * 3 + 2];
            v[0] = f2b(dx); v[1] = f2b(dy); v[2] = f2b(dz);
        }
        a4[mt] = v;
    }

    const f32x4 zero4 = {0.f, 0.f, 0.f, 0.f};

    // ---------------- Layer 0: K=160 (4 global ksteps + 1 register kstep) ----
    f32x4 acc[4][4];
#pragma unroll
    for (int mt = 0; mt < 4; ++mt)
#pragma unroll
        for (int nt = 0; nt < 4; ++nt) acc[mt][nt] = zero4;

#pragma unroll
    for (int ks = 0; ks < 4; ++ks) {
        bf16x8 af[4], bf[4];
#pragma unroll
        for (int mt = 0; mt < 4; ++mt)
            af[mt] = *(const bf16x8*)(feat2b + ((size_t)b * N2_ + jrow[mt]) * 128 + ks * 32 + q * 8);
#pragma unroll
        for (int nt = 0; nt < 4; ++nt)
            bf[nt] = *(const bf16x8*)(W0T + (nBase + nt * 16 + l15) * 160 + ks * 32 + q * 8);
#pragma unroll
        for (int mt = 0; mt < 4; ++mt)
#pragma unroll
            for (int nt = 0; nt < 4; ++nt)
                acc[mt][nt] = __builtin_amdgcn_mfma_f32_16x16x32_bf16(af[mt], bf[nt], acc[mt][nt], 0, 0, 0);
    }
    {   // ks = 4 (k 128..159): A from registers, B from W0T (zero-padded rows)
        bf16x8 bf[4];
#pragma unroll
        for (int nt = 0; nt < 4; ++nt)
            bf[nt] = *(const bf16x8*)(W0T + (nBase + nt * 16 + l15) * 160 + 128 + q * 8);
#pragma unroll
        for (int mt = 0; mt < 4; ++mt)
#pragma unroll
            for (int nt = 0; nt < 4; ++nt)
                acc[mt][nt] = __builtin_amdgcn_mfma_f32_16x16x32_bf16(a4[mt], bf[nt], acc[mt][nt], 0, 0, 0);
    }

    // bias + relu -> sA1 (write-first buffer; no barrier needed before)
    float b0v[4];
#pragma unroll
    for (int nt = 0; nt < 4; ++nt) b0v[nt] = b0[nBase + nt * 16 + l15];
#pragma unroll
    for (int mt = 0; mt < 4; ++mt)
#pragma unroll
        for (int nt = 0; nt < 4; ++nt)
#pragma unroll
            for (int r = 0; r < 4; ++r) {
                const int row = mBase + mt * 16 + q * 4 + r;
                const int col = nBase + nt * 16 + l15;
                sA1[row * 136 + col] = f2b(fmaxf(acc[mt][nt][r] + b0v[nt], 0.0f));
            }
    __syncthreads();

    // ---------------- Layer 1: K=128 (4 ksteps) ----------------
    f32x4 acc2[4][4];
#pragma unroll
    for (int mt = 0; mt < 4; ++mt)
#pragma unroll
        for (int nt = 0; nt < 4; ++nt) acc2[mt][nt] = zero4;

#pragma unroll
    for (int ks = 0; ks < 4; ++ks) {
        bf16x8 af[4], bf[4];
#pragma unroll
        for (int mt = 0; mt < 4; ++mt)
            af[mt] = *(const bf16x8*)(sA1 + (mBase + mt * 16 + l15) * 136 + ks * 32 + q * 8);
#pragma unroll
        for (int nt = 0; nt < 4; ++nt)
            bf[nt] = *(const bf16x8*)(W1T + (nBase + nt * 16 + l15) * 128 + ks * 32 + q * 8);
#pragma unroll
        for (int mt = 0; mt < 4; ++mt)
#pragma unroll
            for (int nt = 0; nt < 4; ++nt)
                acc2[mt][nt] = __builtin_amdgcn_mfma_f32_16x16x32_bf16(af[mt], bf[nt], acc2[mt][nt], 0, 0, 0);
    }

    // bias + relu + in-register maxpool over 8 neighbors -> sCat cols 0..127
    float b1v[4];
#pragma unroll
    for (int nt = 0; nt < 4; ++nt) b1v[nt] = b1[nBase + nt * 16 + l15];
#pragma unroll
    for (int mt = 0; mt < 4; ++mt)
#pragma unroll
        for (int nt = 0; nt < 4; ++nt) {
            float vm = fmaxf(acc2[mt][nt][0] + b1v[nt], 0.0f);
#pragma unroll
            for (int r = 1; r < 4; ++r) vm = fmaxf(vm, acc2[mt][nt][r] + b1v[nt]);
            const float other = __shfl_xor(vm, 16);
            const float pool = fmaxf(vm, other);  // q0/q1 -> even pt, q2/q3 -> odd pt
            if ((q & 1) == 0) {
                const int pp = (mBase >> 3) + mt * 2 + (q >> 1);
                sCat[pp * 200 + nBase + nt * 16 + l15] = f2b(pool);
            }
        }
    __syncthreads();

    // ---------------- Layer 2: M=16 pts, K=192 (6 ksteps), wave owns 32 cols ----
    f32x4 acc3[2];
    acc3[0] = zero4; acc3[1] = zero4;
    const int nB2 = wave * 32;
#pragma unroll
    for (int ks = 0; ks < 6; ++ks) {
        const bf16x8 a2 = *(const bf16x8*)(sCat + l15 * 200 + ks * 32 + q * 8);
#pragma unroll
        for (int nt = 0; nt < 2; ++nt) {
            const bf16x8 b2f = *(const bf16x8*)(W2T + (nB2 + nt * 16 + l15) * 192 + ks * 32 + q * 8);
            acc3[nt] = __builtin_amdgcn_mfma_f32_16x16x32_bf16(a2, b2f, acc3[nt], 0, 0, 0);
        }
    }
    float b2v[2];
#pragma unroll
    for (int nt = 0; nt < 2; ++nt) b2v[nt] = b2[nB2 + nt * 16 + l15];
#pragma unroll
    for (int nt = 0; nt < 2; ++nt)
#pragma unroll
        for (int r = 0; r < 4; ++r) {
            const int p = q * 4 + r;
            const int col = nB2 + nt * 16 + l15;
            out[((size_t)(b * N1_ + n0 + p)) * 128 + col] = fmaxf(acc3[nt][r] + b2v[nt], 0.0f);
        }
}

extern "C" void kernel_launch(void* const* d_in, const int* in_sizes, int n_in,
                              void* d_out, int out_size, void* d_ws, size_t ws_size,
                              hipStream_t stream) {
    const float* xyz1  = (const float*)d_in[0];
    const float* xyz2  = (const float*)d_in[1];
    const float* feat1 = (const float*)d_in[2];
    const float* feat2 = (const float*)d_in[3];
    const float* W0    = (const float*)d_in[4];
    const float* b0    = (const float*)d_in[5];
    const float* W1    = (const float*)d_in[6];
    const float* b1    = (const float*)d_in[7];
    const float* W2    = (const float*)d_in[8];
    const float* b2    = (const float*)d_in[9];
    float* out = (float*)d_out;

    char* ws = (char*)d_ws;
    int*    idx    = (int*)(ws + 0);            // 2 MB
    short*  feat2b = (short*)(ws + 2097152);    // 4 MB
    short*  W0T    = (short*)(ws + 6291456);    // 40960 B
    short*  W1T    = (short*)(ws + 6332416);    // 32768 B
    short*  W2T    = (short*)(ws + 6365184);    // 49152 B
    float4* xpack  = (float4*)(ws + 6414336);   // 256 KB

    prep_feat2<<<2048, 256, 0, stream>>>(feat2, feat2b);
    prep_weights<<<304, 256, 0, stream>>>(W0, W1, W2, xyz2, W0T, W1T, W2T, xpack);
    knn_list<<<dim3(N1_ / 64, B_), 256, 0, stream>>>(xyz1, xpack, idx);
    fused_mfma<<<dim3(N1_ / 16, B_), 256, 0, stream>>>(xyz1, xyz2, feat1, b0, b1, b2,
                                                       feat2b, W0T, W1T, W2T, idx, out);
}

// Round 8
// 326.035 us; speedup vs baseline: 1.1014x; 1.1014x over previous
//
#include <hip/hip_runtime.h>
#include <hip/hip_bf16.h>

constexpr int B_  = 8;
constexpr int N1_ = 8192;
constexpr int N2_ = 2048;
constexpr int K_  = 8;

typedef short bf16x8 __attribute__((ext_vector_type(8)));
typedef float f32x4  __attribute__((ext_vector_type(4)));

__device__ __forceinline__ short f2b(float x) {
    __hip_bfloat16 h = __float2bfloat16(x);  // RNE
    return *reinterpret_cast<short*>(&h);
}

#define CASU(a, b) { const unsigned _lo = (a) < (b) ? (a) : (b); \
                     const unsigned _hi = (a) < (b) ? (b) : (a); \
                     (a) = _lo; (b) = _hi; }

// ---------------------------------------------------------------------------
// Prep 1: feat2 f32 -> bf16 (2M elems), 4 per thread.
// ---------------------------------------------------------------------------
__global__ __launch_bounds__(256) void prep_feat2(const float* __restrict__ feat2,
                                                  short* __restrict__ feat2b) {
    const int i = blockIdx.x * 256 + threadIdx.x;  // 524288 threads
    const float4 v = ((const float4*)feat2)[i];
    uint2 o;
    o.x = (unsigned short)f2b(v.x) | ((unsigned)(unsigned short)f2b(v.y) << 16);
    o.y = (unsigned short)f2b(v.z) | ((unsigned)(unsigned short)f2b(v.w) << 16);
    ((uint2*)feat2b)[i] = o;
}

// ---------------------------------------------------------------------------
// Prep 2: weights -> transposed bf16 [n][k] (k contiguous), W0 k-padded with
// zeros to 160; also pack xyz2 into float4 for scalar-load KNN.
// ---------------------------------------------------------------------------
__global__ __launch_bounds__(256) void prep_weights(
    const float* __restrict__ W0, const float* __restrict__ W1,
    const float* __restrict__ W2, const float* __restrict__ xyz2,
    short* __restrict__ W0T, short* __restrict__ W1T, short* __restrict__ W2T,
    float4* __restrict__ xpack) {
    int i = blockIdx.x * 256 + threadIdx.x;  // 304*256 = 77824 threads
    if (i < 128 * 160) {
        const int n = i / 160, k = i % 160;
        W0T[i] = (k < 131) ? f2b(W0[k * 128 + n]) : (short)0;
        return;
    }
    i -= 128 * 160;
    if (i < 128 * 128) {
        const int n = i >> 7, k = i & 127;
        W1T[i] = f2b(W1[k * 128 + n]);
        return;
    }
    i -= 128 * 128;
    if (i < 128 * 192) {
        const int n = i / 192, k = i % 192;
        W2T[i] = f2b(W2[k * 128 + n]);
        return;
    }
    i -= 128 * 192;
    // 8*2048 xyz2 points
    xpack[i] = make_float4(xyz2[i * 3 + 0], xyz2[i * 3 + 1], xyz2[i * 3 + 2], 0.f);
}

// ---------------------------------------------------------------------------
// KNN v5 (lazy batch threshold): block = 64 queries x 4 segments of 512.
// Scan: per batch of 8, accept-test against bd[7] FROZEN from the previous
// batch (stale => looser => accept superset: safe), append accepted j's to a
// conflict-free [slot][tid] LDS list, then update the exact running top-8
// VALUES with sorting networks: sort8(batch, 19 CAS) + bitonic split
// min(bd[i], x[7-i]) + bitonic merge (12 CAS). Recovery replays the ORIGINAL
// verified (d,idx) chain over listed candidates in index order => bit-exact
// stable top-8. Overflow (cnt > LCAP) falls back to the full verified scan.
// ---------------------------------------------------------------------------
constexpr int LCAP = 76;   // data slots 0..75; rows 76,77 = trash (78 rows)

__global__ __launch_bounds__(256) void knn_lazy(const float* __restrict__ xyz1,
                                                const float4* __restrict__ xpack,
                                                int* __restrict__ idx) {
    __shared__ __align__(16) unsigned short sMem[78 * 256];  // 39936 B, [slot][tid]
    float* sD = (float*)sMem;             // [64][33] overlay after recovery
    int*   sI = (int*)sMem + 64 * 33;

    const int b = blockIdx.y;
    const int lane = threadIdx.x & 63;   // query within block
    const int s = threadIdx.x >> 6;      // segment 0..3
    const int tid = threadIdx.x;
    const int n = blockIdx.x * 64 + lane;

    const float* q = xyz1 + ((size_t)b * N1_ + n) * 3;
    const float qx = q[0], qy = q[1], qz = q[2];
    const float4* P = xpack + (size_t)b * N2_ + s * 512;

    unsigned bd[K_];
#pragma unroll
    for (int t = 0; t < K_; ++t) bd[t] = __float_as_uint(3.0e38f);
    int cnt = 0;

    for (int j0 = 0; j0 < 512; j0 += 8) {
        unsigned xu[8];
#pragma unroll
        for (int u = 0; u < 8; ++u) {
#pragma clang fp contract(off)
            const float4 p = P[j0 + u];
            const float dx = qx - p.x;
            const float dy = qy - p.y;
            const float dz = qz - p.z;
            const float dx2 = dx * dx;
            const float dy2 = dy * dy;
            const float dz2 = dz * dz;
            xu[u] = __float_as_uint((dx2 + dy2) + dz2);
        }
        // ---- accept + store against FROZEN threshold (superset-safe) ----
        const unsigned thr = bd[K_ - 1];
#pragma unroll
        for (int u = 0; u < 8; ++u) {
            const bool acc = xu[u] < thr;
            const int capped = cnt < LCAP ? cnt : LCAP;
            const int slot = acc ? capped : (LCAP + 1);
            sMem[slot * 256 + tid] = (unsigned short)(j0 + u);
            cnt += acc ? 1 : 0;
        }
        // ---- exact value update: sort8 (19 CAS) ----
        CASU(xu[0], xu[1]); CASU(xu[2], xu[3]); CASU(xu[4], xu[5]); CASU(xu[6], xu[7]);
        CASU(xu[0], xu[2]); CASU(xu[1], xu[3]); CASU(xu[4], xu[6]); CASU(xu[5], xu[7]);
        CASU(xu[1], xu[2]); CASU(xu[5], xu[6]); CASU(xu[0], xu[4]); CASU(xu[3], xu[7]);
        CASU(xu[1], xu[5]); CASU(xu[2], xu[6]);
        CASU(xu[1], xu[4]); CASU(xu[3], xu[6]);
        CASU(xu[2], xu[4]); CASU(xu[3], xu[5]);
        CASU(xu[3], xu[4]);
        // ---- bitonic split: lowest-8 of (bd asc ++ xu desc), bitonic ----
        unsigned t0 = bd[0] < xu[7] ? bd[0] : xu[7];
        unsigned t1 = bd[1] < xu[6] ? bd[1] : xu[6];
        unsigned t2 = bd[2] < xu[5] ? bd[2] : xu[5];
        unsigned t3 = bd[3] < xu[4] ? bd[3] : xu[4];
        unsigned t4 = bd[4] < xu[3] ? bd[4] : xu[3];
        unsigned t5 = bd[5] < xu[2] ? bd[5] : xu[2];
        unsigned t6 = bd[6] < xu[1] ? bd[6] : xu[1];
        unsigned t7 = bd[7] < xu[0] ? bd[7] : xu[0];
        // ---- bitonic merge-8 (12 CAS) -> bd sorted ascending ----
        CASU(t0, t4); CASU(t1, t5); CASU(t2, t6); CASU(t3, t7);
        CASU(t0, t2); CASU(t1, t3); CASU(t4, t6); CASU(t5, t7);
        CASU(t0, t1); CASU(t2, t3); CASU(t4, t5); CASU(t6, t7);
        bd[0] = t0; bd[1] = t1; bd[2] = t2; bd[3] = t3;
        bd[4] = t4; bd[5] = t5; bd[6] = t6; bd[7] = t7;
    }

    // ---- recovery: replay the verified (d,idx) chain over listed candidates ----
    float rd[K_];
    int   ri[K_];
#pragma unroll
    for (int t = 0; t < K_; ++t) { rd[t] = 3.0e38f; ri[t] = 0; }
    const int m = cnt < LCAP ? cnt : LCAP;
    for (int t = 0;; ++t) {
        const bool act = t < m;
        if (!__any(act)) break;
        if (act) {
#pragma clang fp contract(off)
            const int jl = sMem[t * 256 + tid];
            const float4 p = P[jl];
            const float dx = qx - p.x;
            const float dy = qy - p.y;
            const float dz = qz - p.z;
            const float dx2 = dx * dx;
            const float dy2 = dy * dy;
            const float dz2 = dz * dz;
            const float d2 = (dx2 + dy2) + dz2;
            if (d2 < rd[K_ - 1]) {
                rd[K_ - 1] = d2; ri[K_ - 1] = s * 512 + jl;
#pragma unroll
                for (int t2 = K_ - 1; t2 >= 1; --t2) {
                    if (rd[t2] < rd[t2 - 1]) {
                        float td = rd[t2]; rd[t2] = rd[t2 - 1]; rd[t2 - 1] = td;
                        int   ti = ri[t2]; ri[t2] = ri[t2 - 1]; ri[t2 - 1] = ti;
                    }
                }
            }
        }
    }

    // ---- overflow fallback: full verified scan for the (rare) lane ----
    if (__any(cnt > LCAP)) {
        if (cnt > LCAP) {
#pragma unroll
            for (int t = 0; t < K_; ++t) { rd[t] = 3.0e38f; ri[t] = 0; }
            for (int j = 0; j < 512; ++j) {
#pragma clang fp contract(off)
                const float4 p = P[j];
                const float dx = qx - p.x;
                const float dy = qy - p.y;
                const float dz = qz - p.z;
                const float dx2 = dx * dx;
                const float dy2 = dy * dy;
                const float dz2 = dz * dz;
                const float d2 = (dx2 + dy2) + dz2;
                if (d2 < rd[K_ - 1]) {
                    rd[K_ - 1] = d2; ri[K_ - 1] = s * 512 + j;
#pragma unroll
                    for (int t2 = K_ - 1; t2 >= 1; --t2) {
                        if (rd[t2] < rd[t2 - 1]) {
                            float td = rd[t2]; rd[t2] = rd[t2 - 1]; rd[t2 - 1] = td;
                            int   ti = ri[t2]; ri[t2] = ri[t2 - 1]; ri[t2 - 1] = ti;
                        }
                    }
                }
            }
        }
    }

    __syncthreads();  // lists fully consumed before reusing sMem as merge region
#pragma unroll
    for (int t = 0; t < K_; ++t) {
        sD[lane * 33 + s * 8 + t] = rd[t];
        sI[lane * 33 + s * 8 + t] = ri[t];
    }
    __syncthreads();

    if (tid < 64) {
        const int qq = tid;
        int h[4] = {0, 0, 0, 0};
        const int base = (b * N1_ + n) * K_;
#pragma unroll
        for (int t = 0; t < K_; ++t) {
            float best = 3.1e38f;
            int   bidx = 0, bs = 0;
#pragma unroll
            for (int ss = 0; ss < 4; ++ss) {
                if (h[ss] < 8) {
                    const float d = sD[qq * 33 + ss * 8 + h[ss]];
                    if (d < best) { best = d; bidx = sI[qq * 33 + ss * 8 + h[ss]]; bs = ss; }
                }
            }
            h[bs]++;
            idx[base + t] = bidx;
        }
    }
}

// ---------------------------------------------------------------------------
// Fused MFMA MLP (verified R5 version, LDS staging): block = 256 thr (4
// waves) = 16 points = 128 GEMM rows.
//   L0: A0(128x160 LDS, stride 168) x W0T(global) -> A1(LDS, stride 136)
//   L1: A1 x W1T -> in-register relu + maxpool(shfl) -> sCat(16x192, str 200)
//   L2: sCat x W2T -> out (f32)
// MFMA 16x16x32 bf16; C/D: col=lane&15, row=(lane>>4)*4+reg  [m89-verified]
// ---------------------------------------------------------------------------
__global__ __launch_bounds__(256) void fused_mfma(
    const float* __restrict__ xyz1, const float* __restrict__ xyz2,
    const float* __restrict__ feat1,
    const float* __restrict__ b0, const float* __restrict__ b1,
    const float* __restrict__ b2,
    const short* __restrict__ feat2b, const short* __restrict__ W0T,
    const short* __restrict__ W1T, const short* __restrict__ W2T,
    const int* __restrict__ idx, float* __restrict__ out) {
    __shared__ __align__(16) short sA[128 * 168];  // A0; later overlaid by A1 (stride 136)
    __shared__ __align__(16) short sCat[16 * 200];

    const int b = blockIdx.y;
    const int n0 = blockIdx.x * 16;
    const int tid = threadIdx.x;

    // ---- stage A0: rows = p*8+kk; k0..127 = feat2b[j], k128..130 = xyz diff, pad 0 ----
    {
        const int row = tid >> 1, half = tid & 1;
        const int p = row >> 3, kk = row & 7;
        const int n = n0 + p;
        const int j = idx[((size_t)b * N1_ + n) * K_ + kk];
        const uint4* src = (const uint4*)(feat2b + ((size_t)(b * N2_ + j)) * 128 + half * 64);
        uint4* dst = (uint4*)(sA + row * 168 + half * 64);
#pragma unroll
        for (int t = 0; t < 8; ++t) dst[t] = src[t];
        uint4* pad = (uint4*)(sA + row * 168 + 128 + half * 16);
        if (half == 0) {
            const float dx = xyz2[((size_t)b * N2_ + j) * 3 + 0] - xyz1[((size_t)b * N1_ + n) * 3 + 0];
            const float dy = xyz2[((size_t)b * N2_ + j) * 3 + 1] - xyz1[((size_t)b * N1_ + n) * 3 + 1];
            const float dz = xyz2[((size_t)b * N2_ + j) * 3 + 2] - xyz1[((size_t)b * N1_ + n) * 3 + 2];
            uint4 v;
            v.x = (unsigned short)f2b(dx) | ((unsigned)(unsigned short)f2b(dy) << 16);
            v.y = (unsigned short)f2b(dz);
            v.z = 0; v.w = 0;
            pad[0] = v;
            pad[1] = make_uint4(0, 0, 0, 0);
        } else {
            pad[0] = make_uint4(0, 0, 0, 0);
            pad[1] = make_uint4(0, 0, 0, 0);
        }
    }
    // ---- stage feat1 -> sCat cols 128..191 ----
    {
#pragma unroll
        for (int u = 0; u < 4; ++u) {
            const int e = tid * 4 + u;  // 0..1023
            const int p = e >> 6, c = e & 63;
            sCat[p * 200 + 128 + c] = f2b(feat1[((size_t)b * N1_ + n0 + p) * 64 + c]);
        }
    }
    __syncthreads();

    const int wave = tid >> 6, lane = tid & 63;
    const int q = lane >> 4, l15 = lane & 15;
    const int mBase = (wave & 1) * 64, nBase = (wave >> 1) * 64;

    const f32x4 zero4 = {0.f, 0.f, 0.f, 0.f};

    // ---------------- Layer 0: K=160 (5 ksteps) ----------------
    f32x4 acc[4][4];
#pragma unroll
    for (int mt = 0; mt < 4; ++mt)
#pragma unroll
        for (int nt = 0; nt < 4; ++nt) acc[mt][nt] = zero4;

    for (int ks = 0; ks < 5; ++ks) {
        bf16x8 af[4], bf[4];
#pragma unroll
        for (int mt = 0; mt < 4; ++mt)
            af[mt] = *(const bf16x8*)(sA + (mBase + mt * 16 + l15) * 168 + ks * 32 + q * 8);
#pragma unroll
        for (int nt = 0; nt < 4; ++nt)
            bf[nt] = *(const bf16x8*)(W0T + (nBase + nt * 16 + l15) * 160 + ks * 32 + q * 8);
#pragma unroll
        for (int mt = 0; mt < 4; ++mt)
#pragma unroll
            for (int nt = 0; nt < 4; ++nt)
                acc[mt][nt] = __builtin_amdgcn_mfma_f32_16x16x32_bf16(af[mt], bf[nt], acc[mt][nt], 0, 0, 0);
    }

    // bias + relu -> A1 overlay (stride 136)
    float b0v[4];
#pragma unroll
    for (int nt = 0; nt < 4; ++nt) b0v[nt] = b0[nBase + nt * 16 + l15];
    __syncthreads();  // all L0 reads of sA done before overlay writes
#pragma unroll
    for (int mt = 0; mt < 4; ++mt)
#pragma unroll
        for (int nt = 0; nt < 4; ++nt)
#pragma unroll
            for (int r = 0; r < 4; ++r) {
                const int row = mBase + mt * 16 + q * 4 + r;
                const int col = nBase + nt * 16 + l15;
                sA[row * 136 + col] = f2b(fmaxf(acc[mt][nt][r] + b0v[nt], 0.0f));
            }
    __syncthreads();

    // ---------------- Layer 1: K=128 (4 ksteps) ----------------
    f32x4 acc2[4][4];
#pragma unroll
    for (int mt = 0; mt < 4; ++mt)
#pragma unroll
        for (int nt = 0; nt < 4; ++nt) acc2[mt][nt] = zero4;

    for (int ks = 0; ks < 4; ++ks) {
        bf16x8 af[4], bf[4];
#pragma unroll
        for (int mt = 0; mt < 4; ++mt)
            af[mt] = *(const bf16x8*)(sA + (mBase + mt * 16 + l15) * 136 + ks * 32 + q * 8);
#pragma unroll
        for (int nt = 0; nt < 4; ++nt)
            bf[nt] = *(const bf16x8*)(W1T + (nBase + nt * 16 + l15) * 128 + ks * 32 + q * 8);
#pragma unroll
        for (int mt = 0; mt < 4; ++mt)
#pragma unroll
            for (int nt = 0; nt < 4; ++nt)
                acc2[mt][nt] = __builtin_amdgcn_mfma_f32_16x16x32_bf16(af[mt], bf[nt], acc2[mt][nt], 0, 0, 0);
    }

    // bias + relu + in-register maxpool over 8 neighbors -> sCat cols 0..127
    float b1v[4];
#pragma unroll
    for (int nt = 0; nt < 4; ++nt) b1v[nt] = b1[nBase + nt * 16 + l15];
#pragma unroll
    for (int mt = 0; mt < 4; ++mt)
#pragma unroll
        for (int nt = 0; nt < 4; ++nt) {
            float vm = fmaxf(acc2[mt][nt][0] + b1v[nt], 0.0f);
#pragma unroll
            for (int r = 1; r < 4; ++r) vm = fmaxf(vm, acc2[mt][nt][r] + b1v[nt]);
            const float other = __shfl_xor(vm, 16);
            const float pool = fmaxf(vm, other);  // q0/q1 -> even pt, q2/q3 -> odd pt
            if ((q & 1) == 0) {
                const int pp = (mBase >> 3) + mt * 2 + (q >> 1);
                sCat[pp * 200 + nBase + nt * 16 + l15] = f2b(pool);
            }
        }
    __syncthreads();

    // ---------------- Layer 2: M=16 pts, K=192 (6 ksteps), wave owns 32 cols ----
    f32x4 acc3[2];
    acc3[0] = zero4; acc3[1] = zero4;
    const int nB2 = wave * 32;
    for (int ks = 0; ks < 6; ++ks) {
        const bf16x8 a2 = *(const bf16x8*)(sCat + l15 * 200 + ks * 32 + q * 8);
#pragma unroll
        for (int nt = 0; nt < 2; ++nt) {
            const bf16x8 b2f = *(const bf16x8*)(W2T + (nB2 + nt * 16 + l15) * 192 + ks * 32 + q * 8);
            acc3[nt] = __builtin_amdgcn_mfma_f32_16x16x32_bf16(a2, b2f, acc3[nt], 0, 0, 0);
        }
    }
    float b2v[2];
#pragma unroll
    for (int nt = 0; nt < 2; ++nt) b2v[nt] = b2[nB2 + nt * 16 + l15];
#pragma unroll
    for (int nt = 0; nt < 2; ++nt)
#pragma unroll
        for (int r = 0; r < 4; ++r) {
            const int p = q * 4 + r;
            const int col = nB2 + nt * 16 + l15;
            out[((size_t)(b * N1_ + n0 + p)) * 128 + col] = fmaxf(acc3[nt][r] + b2v[nt], 0.0f);
        }
}

extern "C" void kernel_launch(void* const* d_in, const int* in_sizes, int n_in,
                              void* d_out, int out_size, void* d_ws, size_t ws_size,
                              hipStream_t stream) {
    const float* xyz1  = (const float*)d_in[0];
    const float* xyz2  = (const float*)d_in[1];
    const float* feat1 = (const float*)d_in[2];
    const float* feat2 = (const float*)d_in[3];
    const float* W0    = (const float*)d_in[4];
    const float* b0    = (const float*)d_in[5];
    const float* W1    = (const float*)d_in[6];
    const float* b1    = (const float*)d_in[7];
    const float* W2    = (const float*)d_in[8];
    const float* b2    = (const float*)d_in[9];
    float* out = (float*)d_out;

    char* ws = (char*)d_ws;
    int*    idx    = (int*)(ws + 0);            // 2 MB
    short*  feat2b = (short*)(ws + 2097152);    // 4 MB
    short*  W0T    = (short*)(ws + 6291456);    // 40960 B
    short*  W1T    = (short*)(ws + 6332416);    // 32768 B
    short*  W2T    = (short*)(ws + 6365184);    // 49152 B
    float4* xpack  = (float4*)(ws + 6414336);   // 256 KB

    prep_feat2<<<2048, 256, 0, stream>>>(feat2, feat2b);
    prep_weights<<<304, 256, 0, stream>>>(W0, W1, W2, xyz2, W0T, W1T, W2T, xpack);
    knn_lazy<<<dim3(N1_ / 64, B_), 256, 0, stream>>>(xyz1, xpack, idx);
    fused_mfma<<<dim3(N1_ / 16, B_), 256, 0, stream>>>(xyz1, xyz2, feat1, b0, b1, b2,
                                                       feat2b, W0T, W1T, W2T, idx, out);
}